// Round 1
// baseline (706.353 us; speedup 1.0000x reference)
//
#include <hip/hip_runtime.h>
#include <hip/hip_bf16.h>

// Problem constants
#define Bc   128
#define Nc   16
#define Fc   20
#define Dc   4
#define Ec   256
#define Hc   128
#define NBc  10
#define BNc  (Bc*Nc)          // 2048
#define Mrows (BNc*Fc)        // 40960

// ---------------------------------------------------------------------------
// K1: build x[r][e], r = bn*F + f  (bn = b*N + i), e in [0,256)
//   e < 128 : prop  = tanh(ent @ W_prop + b_prop)
//   e >= 128: rel   = sum_{j != i} tanh(diff@Wr[0:4] + dist*Wr[4] + b_rel)
//   plus bemb = sum_k emb[bf[r][k]]
// ---------------------------------------------------------------------------
__global__ __launch_bounds__(256)
void k_build_x(const float* __restrict__ ent, const int* __restrict__ bfeat,
               const float* __restrict__ Wp, const float* __restrict__ bp,
               const float* __restrict__ Wr, const float* __restrict__ br,
               const float* __restrict__ emb, float* __restrict__ x) {
    int r   = blockIdx.x;          // 0..40959
    int f   = r % Fc;
    int bn  = r / Fc;
    int i   = bn % Nc;
    int b   = bn / Nc;
    int tid = threadIdx.x;         // 0..255

    __shared__ float sE[Nc][Dc];
    __shared__ float sDiff[Nc][Dc];
    __shared__ float sDist[Nc];

    if (tid < Nc * Dc) {
        int j = tid >> 2, d = tid & 3;
        sE[j][d] = ent[((b * Nc + j) * Fc + f) * Dc + d];
    }
    __syncthreads();
    if (tid < Nc) {
        float d0 = sE[i][0] - sE[tid][0];
        float d1 = sE[i][1] - sE[tid][1];
        float d2 = sE[i][2] - sE[tid][2];
        float d3 = sE[i][3] - sE[tid][3];
        sDiff[tid][0] = d0; sDiff[tid][1] = d1;
        sDiff[tid][2] = d2; sDiff[tid][3] = d3;
        sDist[tid] = sqrtf(d0 * d0 + d1 * d1);   // only dims 0,1 per reference
    }
    __syncthreads();

    // binary-feature embedding sum (indices identical across block -> L1/L2 hot)
    float bemb = 0.f;
    #pragma unroll
    for (int k = 0; k < NBc; ++k) {
        int idx = bfeat[r * NBc + k];
        bemb += emb[idx * Ec + tid];
    }

    float entv;
    if (tid < Hc) {
        float v = bp[tid];
        #pragma unroll
        for (int d = 0; d < Dc; ++d) v = fmaf(sE[i][d], Wp[d * Hc + tid], v);
        entv = tanhf(v);
    } else {
        int h = tid - Hc;
        float w0 = Wr[0 * Hc + h], w1 = Wr[1 * Hc + h], w2 = Wr[2 * Hc + h];
        float w3 = Wr[3 * Hc + h], w4 = Wr[4 * Hc + h], bb = br[h];
        float s = 0.f;
        #pragma unroll
        for (int j = 0; j < Nc; ++j) {
            if (j == i) continue;           // diagonal zeroed in reference
            float v = bb;
            v = fmaf(sDiff[j][0], w0, v);
            v = fmaf(sDiff[j][1], w1, v);
            v = fmaf(sDiff[j][2], w2, v);
            v = fmaf(sDiff[j][3], w3, v);
            v = fmaf(sDist[j],    w4, v);
            s += tanhf(v);
        }
        entv = s;
    }
    x[r * Ec + tid] = entv + bemb;
}

// ---------------------------------------------------------------------------
// K2: gi = x @ w_ih + b_ih    (40960 x 256) @ (256 x 768)
// Tiled fp32 GEMM: BM=64, BN=64, BK=16, 256 threads, 4x4 micro-tile.
// ---------------------------------------------------------------------------
__global__ __launch_bounds__(256)
void k_gemm_gi(const float* __restrict__ A, const float* __restrict__ Bm,
               const float* __restrict__ bias, float* __restrict__ C) {
    __shared__ float As[16][68];   // [kk][m]  (A-tile transposed, +4 pad)
    __shared__ float Bs[16][68];   // [kk][n]
    int m0  = blockIdx.x * 64;
    int n0  = blockIdx.y * 64;
    int tid = threadIdx.x;
    int tx  = tid & 15;            // micro col group (n)
    int ty  = tid >> 4;            // micro row group (m)

    float acc[4][4] = {};

    for (int kc = 0; kc < 256; kc += 16) {
        {   // A tile 64x16 -> As[kk][r]
            int kk = tid & 15;
            int r  = tid >> 4;
            #pragma unroll
            for (int it = 0; it < 4; ++it)
                As[kk][r + it * 16] = A[(m0 + r + it * 16) * Ec + kc + kk];
        }
        {   // B tile 16x64 -> Bs[kk][c]
            int c  = tid & 63;
            int kk = tid >> 6;
            #pragma unroll
            for (int it = 0; it < 4; ++it)
                Bs[kk + it * 4][c] = Bm[(kc + kk + it * 4) * 768 + n0 + c];
        }
        __syncthreads();
        #pragma unroll
        for (int kk = 0; kk < 16; ++kk) {
            float4 a  = *(const float4*)&As[kk][ty * 4];
            float4 bv = *(const float4*)&Bs[kk][tx * 4];
            float av[4]  = {a.x, a.y, a.z, a.w};
            float bvv[4] = {bv.x, bv.y, bv.z, bv.w};
            #pragma unroll
            for (int ii = 0; ii < 4; ++ii)
                #pragma unroll
                for (int jj = 0; jj < 4; ++jj)
                    acc[ii][jj] = fmaf(av[ii], bvv[jj], acc[ii][jj]);
        }
        __syncthreads();
    }

    #pragma unroll
    for (int ii = 0; ii < 4; ++ii) {
        int m = m0 + ty * 4 + ii;
        int c = n0 + tx * 4;
        float4 o;
        o.x = acc[ii][0] + bias[c + 0];
        o.y = acc[ii][1] + bias[c + 1];
        o.z = acc[ii][2] + bias[c + 2];
        o.w = acc[ii][3] + bias[c + 3];
        *(float4*)&C[m * 768 + c] = o;
    }
}

// ---------------------------------------------------------------------------
// K3: one GRU step.  gh = h @ w_hh + b_hh fused with gate pointwise.
// 256 blocks x 8 rows, 256 threads (thread = e).  Torch gate order (r,z,n).
// ---------------------------------------------------------------------------
template<bool FIRST>
__global__ __launch_bounds__(256)
void k_gru_step(const float* __restrict__ gi, const float* __restrict__ Whh,
                const float* __restrict__ bhh, const float* __restrict__ hprev,
                float* __restrict__ hnext, int f) {
    int blk = blockIdx.x;
    int tid = threadIdx.x;     // e
    __shared__ float hs[8][256];
    float accr[8] = {}, accz[8] = {}, accn[8] = {};

    if (!FIRST) {
        #pragma unroll
        for (int rr = 0; rr < 8; ++rr)
            hs[rr][tid] = hprev[(blk * 8 + rr) * Ec + tid];
        __syncthreads();
        for (int k = 0; k < Ec; ++k) {
            float wr = Whh[k * 768 + tid];
            float wz = Whh[k * 768 + 256 + tid];
            float wn = Whh[k * 768 + 512 + tid];
            #pragma unroll
            for (int rr = 0; rr < 8; ++rr) {
                float hk = hs[rr][k];
                accr[rr] = fmaf(hk, wr, accr[rr]);
                accz[rr] = fmaf(hk, wz, accz[rr]);
                accn[rr] = fmaf(hk, wn, accn[rr]);
            }
        }
    }

    float br_ = bhh[tid], bz_ = bhh[256 + tid], bn_ = bhh[512 + tid];
    #pragma unroll
    for (int rr = 0; rr < 8; ++rr) {
        int row = blk * 8 + rr;                       // bn
        const float* girow = gi + (row * Fc + f) * 768;
        float ir  = girow[tid];
        float iz  = girow[256 + tid];
        float in_ = girow[512 + tid];
        float hr = accr[rr] + br_;
        float hz = accz[rr] + bz_;
        float hn = accn[rr] + bn_;
        float rg = 1.f / (1.f + expf(-(ir + hr)));
        float zg = 1.f / (1.f + expf(-(iz + hz)));
        float ng = tanhf(in_ + rg * hn);
        float hp = FIRST ? 0.f : hs[rr][tid];
        hnext[row * Ec + tid] = (1.f - zg) * ng + zg * hp;
    }
}

// ---------------------------------------------------------------------------
extern "C" void kernel_launch(void* const* d_in, const int* in_sizes, int n_in,
                              void* d_out, int out_size, void* d_ws, size_t ws_size,
                              hipStream_t stream) {
    const float* ent  = (const float*)d_in[0];
    const int*   bfeat= (const int*)  d_in[1];
    const float* Wp   = (const float*)d_in[2];
    const float* bp   = (const float*)d_in[3];
    const float* Wr   = (const float*)d_in[4];
    const float* br   = (const float*)d_in[5];
    const float* emb  = (const float*)d_in[6];
    const float* wih  = (const float*)d_in[7];
    const float* bih  = (const float*)d_in[8];
    const float* whh  = (const float*)d_in[9];
    const float* bhh  = (const float*)d_in[10];
    float* out = (float*)d_out;

    char* ws = (char*)d_ws;
    float* x  = (float*)ws;                                   // 40 MB
    float* gi = (float*)(ws + (size_t)Mrows * Ec * 4);        // 120 MB
    char*  hbase = ws + (size_t)Mrows * Ec * 4 + (size_t)Mrows * 768 * 4;
    float* hA = (float*)hbase;                                // 2 MB
    float* hB = (float*)(hbase + (size_t)BNc * Ec * 4);       // 2 MB

    k_build_x<<<Mrows, 256, 0, stream>>>(ent, bfeat, Wp, bp, Wr, br, emb, x);

    dim3 g2(Mrows / 64, 768 / 64);
    k_gemm_gi<<<g2, 256, 0, stream>>>(x, wih, bih, gi);

    float* bufs[2] = {hA, hB};
    k_gru_step<true><<<BNc / 8, 256, 0, stream>>>(gi, whh, bhh, nullptr, bufs[0], 0);
    for (int f = 1; f < Fc; ++f) {
        float* src = bufs[(f + 1) & 1];
        float* dst = (f == Fc - 1) ? out : bufs[f & 1];
        k_gru_step<false><<<BNc / 8, 256, 0, stream>>>(gi, whh, bhh, src, dst, f);
    }
}

// Round 2
// 337.226 us; speedup vs baseline: 2.0946x; 2.0946x over previous
//
#include <hip/hip_runtime.h>
#include <hip/hip_bf16.h>

// Problem constants
#define Bc   128
#define Nc   16
#define Fc   20
#define Dc   4
#define Ec   256
#define Hc   128
#define NBc  10
#define BNc  (Bc*Nc)          // 2048
#define Mrows (BNc*Fc)        // 40960

typedef __attribute__((ext_vector_type(8))) short short8;
typedef __attribute__((ext_vector_type(4))) float f32x4;

static __device__ __forceinline__ unsigned short f2bf(float f) {
    union { float f; unsigned u; } v; v.f = f;
    unsigned r = v.u + 0x7fff + ((v.u >> 16) & 1);   // RNE
    return (unsigned short)(r >> 16);
}

// ---------------------------------------------------------------------------
// K0: transpose + bf16-convert a weight matrix  w[256][768] -> wT[768][256]
// ---------------------------------------------------------------------------
__global__ __launch_bounds__(256)
void k_wprep(const float* __restrict__ w, unsigned short* __restrict__ wT) {
    int n = blockIdx.x;        // 0..767
    int k = threadIdx.x;       // 0..255
    wT[n * 256 + k] = f2bf(w[k * 768 + n]);
}

// ---------------------------------------------------------------------------
// K1: build x[r][e] in bf16, r = bn*F + f
// ---------------------------------------------------------------------------
__global__ __launch_bounds__(256)
void k_build_x(const float* __restrict__ ent, const int* __restrict__ bfeat,
               const float* __restrict__ Wp, const float* __restrict__ bp,
               const float* __restrict__ Wr, const float* __restrict__ br,
               const float* __restrict__ emb, unsigned short* __restrict__ x) {
    int r   = blockIdx.x;          // 0..40959
    int f   = r % Fc;
    int bn  = r / Fc;
    int i   = bn % Nc;
    int b   = bn / Nc;
    int tid = threadIdx.x;         // 0..255

    __shared__ float sE[Nc][Dc];
    __shared__ float sDiff[Nc][Dc];
    __shared__ float sDist[Nc];

    if (tid < Nc * Dc) {
        int j = tid >> 2, d = tid & 3;
        sE[j][d] = ent[((b * Nc + j) * Fc + f) * Dc + d];
    }
    __syncthreads();
    if (tid < Nc) {
        float d0 = sE[i][0] - sE[tid][0];
        float d1 = sE[i][1] - sE[tid][1];
        float d2 = sE[i][2] - sE[tid][2];
        float d3 = sE[i][3] - sE[tid][3];
        sDiff[tid][0] = d0; sDiff[tid][1] = d1;
        sDiff[tid][2] = d2; sDiff[tid][3] = d3;
        sDist[tid] = sqrtf(d0 * d0 + d1 * d1);   // only dims 0,1 per reference
    }
    __syncthreads();

    float bemb = 0.f;
    #pragma unroll
    for (int k = 0; k < NBc; ++k) {
        int idx = bfeat[r * NBc + k];
        bemb += emb[idx * Ec + tid];
    }

    float entv;
    if (tid < Hc) {
        float v = bp[tid];
        #pragma unroll
        for (int d = 0; d < Dc; ++d) v = fmaf(sE[i][d], Wp[d * Hc + tid], v);
        entv = tanhf(v);
    } else {
        int h = tid - Hc;
        float w0 = Wr[0 * Hc + h], w1 = Wr[1 * Hc + h], w2 = Wr[2 * Hc + h];
        float w3 = Wr[3 * Hc + h], w4 = Wr[4 * Hc + h], bb = br[h];
        float s = 0.f;
        #pragma unroll
        for (int j = 0; j < Nc; ++j) {
            if (j == i) continue;           // diagonal skipped in reference
            float v = bb;
            v = fmaf(sDiff[j][0], w0, v);
            v = fmaf(sDiff[j][1], w1, v);
            v = fmaf(sDiff[j][2], w2, v);
            v = fmaf(sDiff[j][3], w3, v);
            v = fmaf(sDist[j],    w4, v);
            s += tanhf(v);
        }
        entv = s;
    }
    x[r * Ec + tid] = f2bf(entv + bemb);
}

// ---------------------------------------------------------------------------
// K2: gi = x @ w_ih + b_ih via bf16 MFMA, direct-from-global fragments.
// Block = 16 rows x full 768 cols; 4 waves, wave w owns cols [w*192,(w+1)*192).
// A-frag: lane(row=l&15, k=(l>>4)*8+j) ; B-frag from wT[n][k] (transposed).
// D-map: col = l&15, row = (l>>4)*4 + reg.
// ---------------------------------------------------------------------------
__global__ __launch_bounds__(256)
void k_gi_mfma(const unsigned short* __restrict__ x,
               const unsigned short* __restrict__ wT,
               const float* __restrict__ bih, float* __restrict__ gi) {
    int m0 = blockIdx.x * 16;
    int w  = threadIdx.x >> 6;
    int l  = threadIdx.x & 63;
    int lr = l & 15;
    int lg = l >> 4;

    f32x4 acc[12] = {};
    for (int kk = 0; kk < 8; ++kk) {
        int k0 = kk * 32 + lg * 8;
        short8 a = *(const short8*)(x + (size_t)(m0 + lr) * 256 + k0);
        #pragma unroll
        for (int t = 0; t < 12; ++t) {
            int n = w * 192 + t * 16 + lr;
            short8 b = *(const short8*)(wT + (size_t)n * 256 + k0);
            acc[t] = __builtin_amdgcn_mfma_f32_16x16x32_bf16(a, b, acc[t], 0, 0, 0);
        }
    }
    #pragma unroll
    for (int t = 0; t < 12; ++t) {
        int col = w * 192 + t * 16 + lr;
        float bv = bih[col];
        #pragma unroll
        for (int j = 0; j < 4; ++j) {
            int row = m0 + lg * 4 + j;
            gi[(size_t)row * 768 + col] = acc[t][j] + bv;
        }
    }
}

// ---------------------------------------------------------------------------
// K3: fully fused GRU. 128 blocks x 16 rows; rows are independent sequences.
// h master in registers (fp32), bf16 copy in LDS as MFMA A-operand.
// Wave w owns h-cols e in [w*64,(w+1)*64) => gate cols {e, e+256, e+512}:
// the (r,z,n) triplet for an h-element lands in the SAME lane & reg.
// ---------------------------------------------------------------------------
#define HSTR 264   // row stride in bf16: 528 B = 33*16 -> aligned + conflict-free

__global__ __launch_bounds__(256)
void k_gru_fused(const float* __restrict__ gi,
                 const unsigned short* __restrict__ whhT,
                 const float* __restrict__ bhh, float* __restrict__ out) {
    __shared__ __align__(16) unsigned short hb[16 * HSTR];
    int bn0 = blockIdx.x * 16;
    int w = threadIdx.x >> 6, l = threadIdx.x & 63;
    int lr = l & 15, lg = l >> 4;

    for (int t = threadIdx.x; t < 16 * HSTR; t += 256) hb[t] = 0;

    float bR[4], bZ[4], bN[4];
    #pragma unroll
    for (int et = 0; et < 4; ++et) {
        int e = w * 64 + et * 16 + lr;
        bR[et] = bhh[e]; bZ[et] = bhh[256 + e]; bN[et] = bhh[512 + e];
    }
    float hold[16] = {};   // [et*4+j] = h[row=lg*4+j][e(et)]

    __syncthreads();

    for (int f = 0; f < Fc; ++f) {
        // prefetch gi for this step (overlaps with MFMA below)
        float gv[12][4];
        #pragma unroll
        for (int t = 0; t < 12; ++t) {
            int g = t >> 2, et = t & 3;
            int col = g * 256 + w * 64 + et * 16 + lr;
            #pragma unroll
            for (int j = 0; j < 4; ++j) {
                int row = bn0 + lg * 4 + j;
                gv[t][j] = gi[((size_t)row * Fc + f) * 768 + col];
            }
        }

        // gh = h @ w_hh  (bf16 MFMA, A from LDS, B from L2-resident whhT)
        f32x4 acc[12] = {};
        for (int kk = 0; kk < 8; ++kk) {
            int k0 = kk * 32 + lg * 8;
            short8 a = *(const short8*)&hb[lr * HSTR + k0];
            #pragma unroll
            for (int t = 0; t < 12; ++t) {
                int g = t >> 2, et = t & 3;
                int n = g * 256 + w * 64 + et * 16 + lr;
                short8 b = *(const short8*)(whhT + (size_t)n * 256 + k0);
                acc[t] = __builtin_amdgcn_mfma_f32_16x16x32_bf16(a, b, acc[t], 0, 0, 0);
            }
        }
        __syncthreads();   // all waves done reading hb

        bool last = (f == Fc - 1);
        #pragma unroll
        for (int et = 0; et < 4; ++et) {
            int e = w * 64 + et * 16 + lr;
            #pragma unroll
            for (int j = 0; j < 4; ++j) {
                float rp = gv[et][j]     + acc[et][j]     + bR[et];
                float zp = gv[4 + et][j] + acc[4 + et][j] + bZ[et];
                float rg = 1.f / (1.f + __expf(-rp));
                float zg = 1.f / (1.f + __expf(-zp));
                float hn = acc[8 + et][j] + bN[et];
                float ng = tanhf(gv[8 + et][j] + rg * hn);
                float h  = hold[et * 4 + j];
                h = (1.f - zg) * ng + zg * h;
                hold[et * 4 + j] = h;
                int row = lg * 4 + j;
                if (last) out[(size_t)(bn0 + row) * Ec + e] = h;
                else      hb[row * HSTR + e] = f2bf(h);
            }
        }
        __syncthreads();   // hb writes visible before next step's MFMA
    }
}

// ---------------------------------------------------------------------------
extern "C" void kernel_launch(void* const* d_in, const int* in_sizes, int n_in,
                              void* d_out, int out_size, void* d_ws, size_t ws_size,
                              hipStream_t stream) {
    const float* ent  = (const float*)d_in[0];
    const int*   bfeat= (const int*)  d_in[1];
    const float* Wp   = (const float*)d_in[2];
    const float* bp   = (const float*)d_in[3];
    const float* Wr   = (const float*)d_in[4];
    const float* br   = (const float*)d_in[5];
    const float* emb  = (const float*)d_in[6];
    const float* wih  = (const float*)d_in[7];
    const float* bih  = (const float*)d_in[8];
    const float* whh  = (const float*)d_in[9];
    const float* bhh  = (const float*)d_in[10];
    float* out = (float*)d_out;

    char* ws = (char*)d_ws;
    unsigned short* x    = (unsigned short*)ws;                       // 21 MB
    float*          gi   = (float*)(ws + (size_t)Mrows * Ec * 2);     // 126 MB
    unsigned short* wihT = (unsigned short*)(ws + (size_t)Mrows * Ec * 2
                                                + (size_t)Mrows * 768 * 4);
    unsigned short* whhT = wihT + (size_t)768 * 256;

    k_wprep<<<768, 256, 0, stream>>>(wih, wihT);
    k_wprep<<<768, 256, 0, stream>>>(whh, whhT);

    k_build_x<<<Mrows, 256, 0, stream>>>(ent, bfeat, Wp, bp, Wr, br, emb, x);

    k_gi_mfma<<<Mrows / 16, 256, 0, stream>>>(x, wihT, bih, gi);

    k_gru_fused<<<BNc / 16, 256, 0, stream>>>(gi, whhT, bhh, out);
}